// Round 1
// baseline (684.517 us; speedup 1.0000x reference)
//
#include <hip/hip_runtime.h>
#include <math.h>

#define H_ 128
#define W_ 160
#define D_ 48
#define C_ 32
#define HW_ (H_ * W_)
#define DHW_ (D_ * HW_)
#define CHW_ (C_ * HW_)

// ---------------------------------------------------------------------------
// Kernel 1: projection setup. Computes, for each src view v=1..4:
//   M0 = ref_proj_new (K0[:3,:3] @ E0[:3,:4], row3 from E0)
//   Mv = src_proj_new
//   P  = Mv @ inv(M0);  rot = P[:3,:3], trans = P[:3,3]
// Stored in ws as 12 floats per view: [r00..r22, t0, t1, t2]
// ---------------------------------------------------------------------------
__device__ __forceinline__ void build_proj(const float* __restrict__ P, int v,
                                           double M[4][4]) {
    const float* E = P + (v * 2 + 0) * 16;
    const float* K = P + (v * 2 + 1) * 16;
    for (int i = 0; i < 3; i++)
        for (int j = 0; j < 4; j++) {
            double s = 0.0;
            for (int k = 0; k < 3; k++) s += (double)K[i * 4 + k] * (double)E[k * 4 + j];
            M[i][j] = s;
        }
    for (int j = 0; j < 4; j++) M[3][j] = (double)E[12 + j];
}

__global__ void proj_kernel(const float* __restrict__ P, float* __restrict__ rt) {
    if (threadIdx.x != 0) return;
    double M0[4][4];
    build_proj(P, 0, M0);
    // Gauss-Jordan inverse with partial pivoting (doubles)
    double a[4][8];
    for (int i = 0; i < 4; i++)
        for (int j = 0; j < 4; j++) {
            a[i][j] = M0[i][j];
            a[i][4 + j] = (i == j) ? 1.0 : 0.0;
        }
    for (int col = 0; col < 4; ++col) {
        int piv = col;
        double best = fabs(a[col][col]);
        for (int r = col + 1; r < 4; r++) {
            double vv = fabs(a[r][col]);
            if (vv > best) { best = vv; piv = r; }
        }
        if (piv != col)
            for (int j = 0; j < 8; j++) {
                double t = a[col][j]; a[col][j] = a[piv][j]; a[piv][j] = t;
            }
        double inv = 1.0 / a[col][col];
        for (int j = 0; j < 8; j++) a[col][j] *= inv;
        for (int r = 0; r < 4; r++)
            if (r != col) {
                double f = a[r][col];
                for (int j = 0; j < 8; j++) a[r][j] -= f * a[col][j];
            }
    }
    double Minv[4][4];
    for (int i = 0; i < 4; i++)
        for (int j = 0; j < 4; j++) Minv[i][j] = a[i][4 + j];

    for (int v = 1; v < 5; ++v) {
        double Mv[4][4];
        build_proj(P, v, Mv);
        double Pm[4][4];
        for (int i = 0; i < 4; i++)
            for (int j = 0; j < 4; j++) {
                double s = 0.0;
                for (int k = 0; k < 4; k++) s += Mv[i][k] * Minv[k][j];
                Pm[i][j] = s;
            }
        float* o = rt + (v - 1) * 12;
        o[0] = (float)Pm[0][0]; o[1] = (float)Pm[0][1]; o[2] = (float)Pm[0][2];
        o[3] = (float)Pm[1][0]; o[4] = (float)Pm[1][1]; o[5] = (float)Pm[1][2];
        o[6] = (float)Pm[2][0]; o[7] = (float)Pm[2][1]; o[8] = (float)Pm[2][2];
        o[9] = (float)Pm[0][3]; o[10] = (float)Pm[1][3]; o[11] = (float)Pm[2][3];
    }
}

// ---------------------------------------------------------------------------
// Kernel 2: warp + bilinear + ref*warped accumulate over 4 views.
// One thread per (d, y, x); loops 32 channels in registers.
// vol[c][d][y][x] = (1/4) * sum_v ref[v][c][y][x] * bilin(src[v][c], px, py)
// ---------------------------------------------------------------------------
__global__ void warp_kernel(const float* __restrict__ src_feats,
                            const float* __restrict__ ref_feats,
                            const float* __restrict__ rt,
                            const float* __restrict__ dvals,
                            float* __restrict__ vol) {
    int idx = blockIdx.x * blockDim.x + threadIdx.x;
    if (idx >= DHW_) return;
    int x = idx % W_;
    int y = (idx / W_) % H_;
    int d = idx / HW_;
    float depth = dvals[d];
    float xf = (float)x, yf = (float)y;
    int pix = y * W_ + x;

    float acc[C_];
#pragma unroll
    for (int c = 0; c < C_; c++) acc[c] = 0.f;

#pragma unroll 1
    for (int v = 0; v < 4; v++) {
        const float* m = rt + v * 12;
        float px = fmaf(fmaf(m[0], xf, fmaf(m[1], yf, m[2])), depth, m[9]);
        float py = fmaf(fmaf(m[3], xf, fmaf(m[4], yf, m[5])), depth, m[10]);
        float pz = fmaf(fmaf(m[6], xf, fmaf(m[7], yf, m[8])), depth, m[11]);
        float iz = 1.f / pz;
        px *= iz;
        py *= iz;
        float x0f = floorf(px), y0f = floorf(py);
        float wx = px - x0f, wy = py - y0f;
        int x0 = (int)x0f, y0 = (int)y0f;
        int x1 = x0 + 1, y1 = y0 + 1;

        float w00 = (1.f - wx) * (1.f - wy);
        float w10 = wx * (1.f - wy);
        float w01 = (1.f - wx) * wy;
        float w11 = wx * wy;
        bool vx0 = (x0 >= 0) && (x0 < W_);
        bool vx1 = (x1 >= 0) && (x1 < W_);
        bool vy0 = (y0 >= 0) && (y0 < H_);
        bool vy1 = (y1 >= 0) && (y1 < H_);
        if (!(vx0 && vy0)) w00 = 0.f;
        if (!(vx1 && vy0)) w10 = 0.f;
        if (!(vx0 && vy1)) w01 = 0.f;
        if (!(vx1 && vy1)) w11 = 0.f;
        int cx0 = min(max(x0, 0), W_ - 1);
        int cx1 = min(max(x1, 0), W_ - 1);
        int cy0 = min(max(y0, 0), H_ - 1);
        int cy1 = min(max(y1, 0), H_ - 1);
        int o00 = cy0 * W_ + cx0;
        int o10 = cy0 * W_ + cx1;
        int o01 = cy1 * W_ + cx0;
        int o11 = cy1 * W_ + cx1;

        const float* s = src_feats + v * CHW_;
        const float* r = ref_feats + v * CHW_;
#pragma unroll
        for (int c = 0; c < C_; c++) {
            const float* sc = s + c * HW_;
            float sv = w00 * sc[o00] + w10 * sc[o10] + w01 * sc[o01] + w11 * sc[o11];
            acc[c] = fmaf(r[c * HW_ + pix], sv, acc[c]);
        }
    }
#pragma unroll
    for (int c = 0; c < C_; c++) vol[c * DHW_ + idx] = acc[c] * 0.25f;
}

// ---------------------------------------------------------------------------
// Kernel 3: 3x3x3 conv (cross-correlation, zero 'SAME' padding) over (D,H,W),
// summing 32 channels to 1 output channel.
// ---------------------------------------------------------------------------
__global__ void conv_kernel(const float* __restrict__ vol,
                            const float* __restrict__ wreg,
                            float* __restrict__ cost) {
    __shared__ float sw[C_ * 27];
    for (int i = threadIdx.x; i < C_ * 27; i += blockDim.x) sw[i] = wreg[i];
    __syncthreads();
    int idx = blockIdx.x * blockDim.x + threadIdx.x;
    if (idx >= DHW_) return;
    int x = idx % W_;
    int y = (idx / W_) % H_;
    int d = idx / HW_;
    float acc = 0.f;
#pragma unroll 1
    for (int c = 0; c < C_; c++) {
        const float* base = vol + c * DHW_;
        const float* wc = sw + c * 27;
#pragma unroll
        for (int kd = 0; kd < 3; kd++) {
            int dd = d + kd - 1;
            if ((unsigned)dd >= (unsigned)D_) continue;
#pragma unroll
            for (int kh = 0; kh < 3; kh++) {
                int yy = y + kh - 1;
                if ((unsigned)yy >= (unsigned)H_) continue;
                const float* row = base + dd * HW_ + yy * W_;
#pragma unroll
                for (int kw = 0; kw < 3; kw++) {
                    int xx = x + kw - 1;
                    if ((unsigned)xx >= (unsigned)W_) continue;
                    acc = fmaf(row[xx], wc[kd * 9 + kh * 3 + kw], acc);
                }
            }
        }
    }
    cost[idx] = acc;
}

// ---------------------------------------------------------------------------
// Kernel 4: per-pixel softmax over D, expected depth, windowed confidence.
// 3 read passes over cost (L2-resident, 3.9MB) -> no runtime-indexed arrays.
// ---------------------------------------------------------------------------
__global__ void softmax_kernel(const float* __restrict__ cost,
                               const float* __restrict__ dvals,
                               float* __restrict__ out) {
    int pix = blockIdx.x * blockDim.x + threadIdx.x;
    if (pix >= HW_) return;
    float mx = -1e30f;
#pragma unroll 1
    for (int d = 0; d < D_; d++) mx = fmaxf(mx, cost[d * HW_ + pix]);
    float s = 0.f, dnum = 0.f, inum = 0.f;
#pragma unroll 1
    for (int d = 0; d < D_; d++) {
        float e = __expf(cost[d * HW_ + pix] - mx);
        s += e;
        dnum = fmaf(e, dvals[d], dnum);
        inum = fmaf(e, (float)d, inum);
    }
    float invs = 1.f / s;
    float depth = dnum * invs;
    float didx = inum * invs;
    int id = (int)didx;
    id = min(max(id, 0), D_ - 1);
    float conf = 0.f;
    for (int k = id - 1; k <= id + 2; ++k)
        if (k >= 0 && k < D_) conf += __expf(cost[k * HW_ + pix] - mx);
    conf *= invs;
    out[pix] = depth;
    out[HW_ + pix] = conf;
}

// ---------------------------------------------------------------------------
extern "C" void kernel_launch(void* const* d_in, const int* in_sizes, int n_in,
                              void* d_out, int out_size, void* d_ws, size_t ws_size,
                              hipStream_t stream) {
    const float* ref_feats = (const float*)d_in[0];   // (4,1,32,128,160)
    const float* src_feats = (const float*)d_in[1];   // (4,1,32,128,160)
    const float* proj      = (const float*)d_in[2];   // (1,5,2,4,4)
    const float* dvals     = (const float*)d_in[3];   // (1,48)
    const float* wreg      = (const float*)d_in[5];   // (1,32,3,3,3)
    float* out = (float*)d_out;                       // depth(20480) ++ conf(20480)

    char* ws = (char*)d_ws;
    float* rt   = (float*)ws;                                   // 48 floats
    float* vol  = (float*)(ws + 1024);                          // 126 MB
    float* cost = (float*)(ws + 1024 + (size_t)DHW_ * C_ * 4);  // 3.9 MB

    proj_kernel<<<1, 64, 0, stream>>>(proj, rt);
    warp_kernel<<<DHW_ / 256, 256, 0, stream>>>(src_feats, ref_feats, rt, dvals, vol);
    conv_kernel<<<DHW_ / 256, 256, 0, stream>>>(vol, wreg, cost);
    softmax_kernel<<<HW_ / 256, 256, 0, stream>>>(cost, dvals, out);
}

// Round 2
// 308.315 us; speedup vs baseline: 2.2202x; 2.2202x over previous
//
#include <hip/hip_runtime.h>
#include <math.h>

#define H_ 128
#define W_ 160
#define D_ 48
#define C_ 32
#define K27 27
#define HW_ (H_ * W_)
#define DHW_ (D_ * HW_)
#define CHW_ (C_ * HW_)

// ---------------------------------------------------------------------------
// Kernel 1: projection setup (unchanged). For each src view v=1..4 store
// 12 floats: rot(9) + trans(3) of  src_proj_new @ inv(ref_proj_new).
// ---------------------------------------------------------------------------
__device__ __forceinline__ void build_proj(const float* __restrict__ P, int v,
                                           double M[4][4]) {
    const float* E = P + (v * 2 + 0) * 16;
    const float* K = P + (v * 2 + 1) * 16;
    for (int i = 0; i < 3; i++)
        for (int j = 0; j < 4; j++) {
            double s = 0.0;
            for (int k = 0; k < 3; k++) s += (double)K[i * 4 + k] * (double)E[k * 4 + j];
            M[i][j] = s;
        }
    for (int j = 0; j < 4; j++) M[3][j] = (double)E[12 + j];
}

__global__ void proj_kernel(const float* __restrict__ P, float* __restrict__ rt) {
    if (threadIdx.x != 0) return;
    double M0[4][4];
    build_proj(P, 0, M0);
    double a[4][8];
    for (int i = 0; i < 4; i++)
        for (int j = 0; j < 4; j++) {
            a[i][j] = M0[i][j];
            a[i][4 + j] = (i == j) ? 1.0 : 0.0;
        }
    for (int col = 0; col < 4; ++col) {
        int piv = col;
        double best = fabs(a[col][col]);
        for (int r = col + 1; r < 4; r++) {
            double vv = fabs(a[r][col]);
            if (vv > best) { best = vv; piv = r; }
        }
        if (piv != col)
            for (int j = 0; j < 8; j++) {
                double t = a[col][j]; a[col][j] = a[piv][j]; a[piv][j] = t;
            }
        double inv = 1.0 / a[col][col];
        for (int j = 0; j < 8; j++) a[col][j] *= inv;
        for (int r = 0; r < 4; r++)
            if (r != col) {
                double f = a[r][col];
                for (int j = 0; j < 8; j++) a[r][j] -= f * a[col][j];
            }
    }
    double Minv[4][4];
    for (int i = 0; i < 4; i++)
        for (int j = 0; j < 4; j++) Minv[i][j] = a[i][4 + j];

    for (int v = 1; v < 5; ++v) {
        double Mv[4][4];
        build_proj(P, v, Mv);
        double Pm[4][4];
        for (int i = 0; i < 4; i++)
            for (int j = 0; j < 4; j++) {
                double s = 0.0;
                for (int k = 0; k < 4; k++) s += Mv[i][k] * Minv[k][j];
                Pm[i][j] = s;
            }
        float* o = rt + (v - 1) * 12;
        o[0] = (float)Pm[0][0]; o[1] = (float)Pm[0][1]; o[2] = (float)Pm[0][2];
        o[3] = (float)Pm[1][0]; o[4] = (float)Pm[1][1]; o[5] = (float)Pm[1][2];
        o[6] = (float)Pm[2][0]; o[7] = (float)Pm[2][1]; o[8] = (float)Pm[2][2];
        o[9] = (float)Pm[0][3]; o[10] = (float)Pm[1][3]; o[11] = (float)Pm[2][3];
    }
}

// ---------------------------------------------------------------------------
// Kernel 2: warp + bilinear + ref*warped accumulate over 4 views, then fold
// the channel dimension through the conv weights IN REGISTERS:
//   acc[c]   = (1/4) sum_v ref[v][c][pix] * bilin(src[v][c], px, py)
//   G[k][p]  = sum_c w[c][k] * acc[c]          (k = 27 conv taps)
// Weights are wave-uniform -> scalar loads (s_load), scalar-cache hot.
// ---------------------------------------------------------------------------
__global__ void warp_fold_kernel(const float* __restrict__ src_feats,
                                 const float* __restrict__ ref_feats,
                                 const float* __restrict__ rt,
                                 const float* __restrict__ dvals,
                                 const float* __restrict__ wreg,
                                 float* __restrict__ G) {
    int idx = blockIdx.x * blockDim.x + threadIdx.x;
    if (idx >= DHW_) return;
    int x = idx % W_;
    int y = (idx / W_) % H_;
    int d = idx / HW_;
    float depth = dvals[d];
    float xf = (float)x, yf = (float)y;
    int pix = y * W_ + x;

    float acc[C_];
#pragma unroll
    for (int c = 0; c < C_; c++) acc[c] = 0.f;

#pragma unroll 1
    for (int v = 0; v < 4; v++) {
        const float* m = rt + v * 12;
        float px = fmaf(fmaf(m[0], xf, fmaf(m[1], yf, m[2])), depth, m[9]);
        float py = fmaf(fmaf(m[3], xf, fmaf(m[4], yf, m[5])), depth, m[10]);
        float pz = fmaf(fmaf(m[6], xf, fmaf(m[7], yf, m[8])), depth, m[11]);
        float iz = 1.f / pz;
        px *= iz;
        py *= iz;
        float x0f = floorf(px), y0f = floorf(py);
        float wx = px - x0f, wy = py - y0f;
        int x0 = (int)x0f, y0 = (int)y0f;
        int x1 = x0 + 1, y1 = y0 + 1;

        float w00 = (1.f - wx) * (1.f - wy);
        float w10 = wx * (1.f - wy);
        float w01 = (1.f - wx) * wy;
        float w11 = wx * wy;
        bool vx0 = (x0 >= 0) && (x0 < W_);
        bool vx1 = (x1 >= 0) && (x1 < W_);
        bool vy0 = (y0 >= 0) && (y0 < H_);
        bool vy1 = (y1 >= 0) && (y1 < H_);
        if (!(vx0 && vy0)) w00 = 0.f;
        if (!(vx1 && vy0)) w10 = 0.f;
        if (!(vx0 && vy1)) w01 = 0.f;
        if (!(vx1 && vy1)) w11 = 0.f;
        int cx0 = min(max(x0, 0), W_ - 1);
        int cx1 = min(max(x1, 0), W_ - 1);
        int cy0 = min(max(y0, 0), H_ - 1);
        int cy1 = min(max(y1, 0), H_ - 1);
        int o00 = cy0 * W_ + cx0;
        int o10 = cy0 * W_ + cx1;
        int o01 = cy1 * W_ + cx0;
        int o11 = cy1 * W_ + cx1;

        const float* s = src_feats + v * CHW_;
        const float* r = ref_feats + v * CHW_;
#pragma unroll
        for (int c = 0; c < C_; c++) {
            const float* sc = s + c * HW_;
            float sv = w00 * sc[o00] + w10 * sc[o10] + w01 * sc[o01] + w11 * sc[o11];
            acc[c] = fmaf(r[c * HW_ + pix], sv, acc[c]);
        }
    }

    // fold channels through conv weights (uniform -> SGPR loads)
    float g[K27];
#pragma unroll
    for (int k = 0; k < K27; k++) g[k] = 0.f;
#pragma unroll
    for (int c = 0; c < C_; c++) {
        float a = acc[c] * 0.25f;
#pragma unroll
        for (int k = 0; k < K27; k++) g[k] = fmaf(wreg[c * K27 + k], a, g[k]);
    }
#pragma unroll
    for (int k = 0; k < K27; k++) G[k * DHW_ + idx] = g[k];
}

// ---------------------------------------------------------------------------
// Kernel 3: gather-conv. cost[d,y,x] = sum over 27 taps of the corresponding
// G plane at the shifted voxel (zero outside). 27 coalesced loads/thread.
// ---------------------------------------------------------------------------
__global__ void gather_conv_kernel(const float* __restrict__ G,
                                   float* __restrict__ cost) {
    int idx = blockIdx.x * blockDim.x + threadIdx.x;
    if (idx >= DHW_) return;
    int x = idx % W_;
    int y = (idx / W_) % H_;
    int d = idx / HW_;
    float acc = 0.f;
#pragma unroll
    for (int kd = 0; kd < 3; kd++) {
        int dd = d + kd - 1;
        bool vd = (unsigned)dd < (unsigned)D_;
#pragma unroll
        for (int kh = 0; kh < 3; kh++) {
            int yy = y + kh - 1;
            bool vy = (unsigned)yy < (unsigned)H_;
#pragma unroll
            for (int kw = 0; kw < 3; kw++) {
                int xx = x + kw - 1;
                bool vx = (unsigned)xx < (unsigned)W_;
                if (vd && vy && vx) {
                    int k = (kd * 3 + kh) * 3 + kw;
                    acc += G[k * DHW_ + dd * HW_ + yy * W_ + xx];
                }
            }
        }
    }
    cost[idx] = acc;
}

// ---------------------------------------------------------------------------
// Kernel 4: per-pixel softmax over D, expected depth, windowed confidence.
// ---------------------------------------------------------------------------
__global__ void softmax_kernel(const float* __restrict__ cost,
                               const float* __restrict__ dvals,
                               float* __restrict__ out) {
    int pix = blockIdx.x * blockDim.x + threadIdx.x;
    if (pix >= HW_) return;
    float mx = -1e30f;
#pragma unroll 1
    for (int d = 0; d < D_; d++) mx = fmaxf(mx, cost[d * HW_ + pix]);
    float s = 0.f, dnum = 0.f, inum = 0.f;
#pragma unroll 1
    for (int d = 0; d < D_; d++) {
        float e = __expf(cost[d * HW_ + pix] - mx);
        s += e;
        dnum = fmaf(e, dvals[d], dnum);
        inum = fmaf(e, (float)d, inum);
    }
    float invs = 1.f / s;
    float depth = dnum * invs;
    float didx = inum * invs;
    int id = (int)didx;
    id = min(max(id, 0), D_ - 1);
    float conf = 0.f;
    for (int k = id - 1; k <= id + 2; ++k)
        if (k >= 0 && k < D_) conf += __expf(cost[k * HW_ + pix] - mx);
    conf *= invs;
    out[pix] = depth;
    out[HW_ + pix] = conf;
}

// ---------------------------------------------------------------------------
extern "C" void kernel_launch(void* const* d_in, const int* in_sizes, int n_in,
                              void* d_out, int out_size, void* d_ws, size_t ws_size,
                              hipStream_t stream) {
    const float* ref_feats = (const float*)d_in[0];   // (4,1,32,128,160)
    const float* src_feats = (const float*)d_in[1];   // (4,1,32,128,160)
    const float* proj      = (const float*)d_in[2];   // (1,5,2,4,4)
    const float* dvals     = (const float*)d_in[3];   // (1,48)
    const float* wreg      = (const float*)d_in[5];   // (1,32,3,3,3)
    float* out = (float*)d_out;                       // depth(20480) ++ conf(20480)

    char* ws = (char*)d_ws;
    float* rt   = (float*)ws;                                    // 48 floats
    float* G    = (float*)(ws + 1024);                           // 27*DHW*4 = 106 MB
    float* cost = (float*)(ws + 1024 + (size_t)K27 * DHW_ * 4);  // 3.9 MB

    proj_kernel<<<1, 64, 0, stream>>>(proj, rt);
    warp_fold_kernel<<<DHW_ / 256, 256, 0, stream>>>(src_feats, ref_feats, rt,
                                                     dvals, wreg, G);
    gather_conv_kernel<<<DHW_ / 256, 256, 0, stream>>>(G, cost);
    softmax_kernel<<<HW_ / 256, 256, 0, stream>>>(cost, dvals, out);
}